// Round 1
// baseline (1119.229 us; speedup 1.0000x reference)
//
#include <hip/hip_runtime.h>
#include <hip/hip_bf16.h>

typedef __bf16 bf16;
typedef __bf16 bf16x8 __attribute__((ext_vector_type(8)));
typedef __bf16 bf16x4 __attribute__((ext_vector_type(4)));
typedef float  f32x4  __attribute__((ext_vector_type(4)));

#define DIM   1024
#define SEQ   2048
#define BATCH 8
#define NROWS (BATCH * SEQ)
#define HID   4096

// ---------------- async global->LDS (16B/lane) ----------------
__device__ __forceinline__ void async_ld16(const bf16* g, bf16* l) {
    __builtin_amdgcn_global_load_lds(
        (__attribute__((address_space(1))) void*)(g),
        (__attribute__((address_space(3))) void*)(l),
        16, 0, 0);
}

__device__ __forceinline__ f32x4 mfma16(bf16x8 a, bf16x8 b, f32x4 c) {
    return __builtin_amdgcn_mfma_f32_16x16x32_bf16(a, b, c, 0, 0, 0);
}

// ---------------- GEMM: C[M,N] = A[M,K] @ Bt[N,K]^T (+epilogue) ----------------
// m97 structure: 128x128 tile, BK=32, 256 threads (4 waves in 2x2), 16 MFMA/K-step.
// BIASMODE: 0 none, 1 bias[n], 2 bias[m]
// SCORE: scale + causal mask (n>m -> -1e30), skip tiles fully above diagonal
// PV: K-loop stops at m0+128 (causal)
template<int OUTF32, int BIASMODE, int RESID, int GELU, int SCORE, int PV>
__global__ __launch_bounds__(256) void gemm_kernel(
    const bf16* __restrict__ A, size_t aB,
    const bf16* __restrict__ B, size_t bB,
    void* __restrict__ Cv, size_t cB,
    const float* __restrict__ bias,
    const float* __restrict__ resid,
    int M, int N, int K, float scale)
{
    __shared__ alignas(16) bf16 As[128 * 32];
    __shared__ alignas(16) bf16 Bs[128 * 32];

    const int m0 = blockIdx.y * 128;
    const int n0 = blockIdx.x * 128;
    if (SCORE && n0 >= m0 + 128) return;   // fully-masked tile: never read downstream

    const int z = blockIdx.z;
    A += (size_t)z * aB;
    B += (size_t)z * bB;

    const int t    = threadIdx.x;
    const int lane = t & 63;
    const int wave = t >> 6;
    const int wm   = wave & 1;
    const int wn   = wave >> 1;

    const int kEnd   = PV ? (m0 + 128) : K;
    const int kIters = kEnd >> 5;

    f32x4 acc[4][4] = {};

    // staging addresses: 128 rows x 32 cols bf16, 4 lanes/row (16B each), 2 calls
    const int sr = t >> 2;
    const int sc = (t & 3) * 8;
    const bf16* gA = A + (size_t)(m0 + sr) * (size_t)K + sc;
    const bf16* gB = B + (size_t)(n0 + sr) * (size_t)K + sc;
    bf16* lA = As + wave * 512;   // wave-uniform LDS base (16 rows/wave/call)
    bf16* lB = Bs + wave * 512;
    const size_t rowStep = (size_t)64 * (size_t)K;

    // fragment read addresses (A[m=lane&15][k=quad*8+j], Bt[n=lane&15][k=quad*8+j])
    const int frow = lane & 15;
    const int k8   = (lane >> 4) * 8;
    const bf16* pa = As + (wm * 64 + frow) * 32 + k8;
    const bf16* pb = Bs + (wn * 64 + frow) * 32 + k8;

    for (int kt = 0; kt < kIters; ++kt) {
        const size_t ko = (size_t)(kt * 32);
        async_ld16(gA + ko,           lA);
        async_ld16(gA + ko + rowStep, lA + 64 * 32);
        async_ld16(gB + ko,           lB);
        async_ld16(gB + ko + rowStep, lB + 64 * 32);
        __syncthreads();

        bf16x8 af[4], bf_[4];
        #pragma unroll
        for (int i = 0; i < 4; ++i) af[i]  = *(const bf16x8*)(pa + i * 16 * 32);
        #pragma unroll
        for (int j = 0; j < 4; ++j) bf_[j] = *(const bf16x8*)(pb + j * 16 * 32);
        #pragma unroll
        for (int i = 0; i < 4; ++i)
            #pragma unroll
            for (int j = 0; j < 4; ++j)
                acc[i][j] = mfma16(af[i], bf_[j], acc[i][j]);
        __syncthreads();
    }

    // epilogue: C/D layout col=lane&15, row=(lane>>4)*4+reg  [m89-verified]
    const int col  = lane & 15;
    const int row4 = (lane >> 4) * 4;
    const size_t cOff = (size_t)z * cB;
    #pragma unroll
    for (int i = 0; i < 4; ++i) {
        const int mBase = m0 + wm * 64 + i * 16 + row4;
        #pragma unroll
        for (int j = 0; j < 4; ++j) {
            const int n = n0 + wn * 64 + j * 16 + col;
            const float bcol = (BIASMODE == 1) ? bias[n] : 0.0f;
            #pragma unroll
            for (int r = 0; r < 4; ++r) {
                const int m = mBase + r;
                float v = acc[i][j][r];
                if (BIASMODE == 1) v += bcol;
                if (BIASMODE == 2) v += bias[m];
                if (SCORE) { v *= scale; if (n > m) v = -1e30f; }
                if (GELU)  { v = 0.5f * v * (1.0f + erff(v * 0.70710678118654752f)); }
                const size_t idx = cOff + (size_t)m * (size_t)N + (size_t)n;
                if (RESID) v += resid[idx];
                if (OUTF32) ((float*)Cv)[idx] = v;
                else        ((bf16*)Cv)[idx]  = (bf16)v;
            }
        }
    }
}

// ---------------- RMSNorm: fp32 row(1024) -> bf16 ----------------
__global__ __launch_bounds__(256) void rmsnorm_kernel(
    const float* __restrict__ x, const float* __restrict__ w, bf16* __restrict__ out)
{
    const int row = blockIdx.x;
    const int t   = threadIdx.x;
    const float4 v = ((const float4*)(x + (size_t)row * DIM))[t];
    float ss = v.x * v.x + v.y * v.y + v.z * v.z + v.w * v.w;
    #pragma unroll
    for (int off = 32; off; off >>= 1) ss += __shfl_down(ss, off);
    __shared__ float part[4];
    if ((t & 63) == 0) part[t >> 6] = ss;
    __syncthreads();
    const float tot  = part[0] + part[1] + part[2] + part[3];
    const float rinv = rsqrtf(tot * (1.0f / DIM) + 1e-6f);
    const float4 wv = ((const float4*)w)[t];
    bf16x4 o;
    o[0] = (bf16)(v.x * rinv * wv.x);
    o[1] = (bf16)(v.y * rinv * wv.y);
    o[2] = (bf16)(v.z * rinv * wv.z);
    o[3] = (bf16)(v.w * rinv * wv.w);
    *(bf16x4*)(out + (size_t)row * DIM + t * 4) = o;
}

// ---------------- weight fp32 [R,C] -> bf16 transposed [C,R] ----------------
__global__ __launch_bounds__(256) void transpose_w_kernel(
    const float* __restrict__ src, bf16* __restrict__ dst, int R, int C)
{
    __shared__ float tile[32][33];
    const int tx = threadIdx.x & 31;
    const int ty = threadIdx.x >> 5;     // 0..7
    const int c0 = blockIdx.x * 32;
    const int r0 = blockIdx.y * 32;
    #pragma unroll
    for (int j = 0; j < 32; j += 8)
        tile[ty + j][tx] = src[(size_t)(r0 + ty + j) * C + c0 + tx];
    __syncthreads();
    #pragma unroll
    for (int j = 0; j < 32; j += 8)
        dst[(size_t)(c0 + ty + j) * R + r0 + tx] = (bf16)tile[tx][ty + j];
}

// ---------------- causal softmax over S rows, in place (bf16) ----------------
// only scans s in [0, roundup128(t+1)); masked entries hold -1e30 -> exp = 0
__global__ __launch_bounds__(256) void softmax_kernel(bf16* __restrict__ S)
{
    const int t = blockIdx.x;
    const int b = blockIdx.y;
    bf16* p = S + ((size_t)b * SEQ + t) * SEQ;
    const int send = ((t >> 7) + 1) << 7;
    const int tid  = threadIdx.x;
    const int lane = tid & 63;
    const int wave = tid >> 6;

    float v[8];
    int cnt = 0;
    float m = -3.0e38f;
    for (int i = tid; i < send; i += 256) { const float f = (float)p[i]; v[cnt++] = f; m = fmaxf(m, f); }
    #pragma unroll
    for (int off = 32; off; off >>= 1) m = fmaxf(m, __shfl_down(m, off));
    __shared__ float red[4];
    if (lane == 0) red[wave] = m;
    __syncthreads();
    m = fmaxf(fmaxf(red[0], red[1]), fmaxf(red[2], red[3]));
    __syncthreads();

    float s = 0.0f;
    for (int k2 = 0; k2 < cnt; ++k2) { v[k2] = __expf(v[k2] - m); s += v[k2]; }
    #pragma unroll
    for (int off = 32; off; off >>= 1) s += __shfl_down(s, off);
    if (lane == 0) red[wave] = s;
    __syncthreads();
    s = red[0] + red[1] + red[2] + red[3];
    const float inv = 1.0f / s;
    cnt = 0;
    for (int i = tid; i < send; i += 256) p[i] = (bf16)(v[cnt++] * inv);
}

extern "C" void kernel_launch(void* const* d_in, const int* in_sizes, int n_in,
                              void* d_out, int out_size, void* d_ws, size_t ws_size,
                              hipStream_t stream)
{
    const float* x   = (const float*)d_in[0];
    const float* anw = (const float*)d_in[1];
    const float* mnw = (const float*)d_in[2];
    const float* wq  = (const float*)d_in[3];
    const float* bq  = (const float*)d_in[4];
    const float* wk  = (const float*)d_in[5];
    const float* bk  = (const float*)d_in[6];
    const float* wv  = (const float*)d_in[7];
    const float* bv  = (const float*)d_in[8];
    const float* wo  = (const float*)d_in[9];
    const float* bo  = (const float*)d_in[10];
    const float* w1  = (const float*)d_in[11];
    const float* b1  = (const float*)d_in[12];
    const float* w2  = (const float*)d_in[13];
    const float* b2  = (const float*)d_in[14];
    float* out = (float*)d_out;

    char* ws = (char*)d_ws;
    const size_t MB = 1024 * 1024;
    bf16* wqT = (bf16*)(ws + 0 * MB);    // 1024x1024  (2 MB)
    bf16* wkT = (bf16*)(ws + 2 * MB);
    bf16* wvT = (bf16*)(ws + 4 * MB);
    bf16* woT = (bf16*)(ws + 6 * MB);
    bf16* w1T = (bf16*)(ws + 8 * MB);    // 4096x1024  (8 MB)
    bf16* w2T = (bf16*)(ws + 16 * MB);   // 1024x4096  (8 MB)
    bf16* xn  = (bf16*)(ws + 24 * MB);   // 16384x1024 (32 MB)
    bf16* q   = (bf16*)(ws + 56 * MB);   // 32 MB
    bf16* k   = (bf16*)(ws + 88 * MB);   // 32 MB
    bf16* vT  = (bf16*)(ws + 120 * MB);  // 8 x 1024 x 2048 (32 MB)
    bf16* S   = (bf16*)(ws + 152 * MB);  // 8 x 2048 x 2048 (64 MB) -> end 216 MB
    bf16* attn = xn;                     // alias: xn dead after vT GEMM
    bf16* h    = q;                      // alias: q dead after score GEMM
    bf16* mid  = k;                      // alias: spans k+vT+S (128 MB), all dead after PV

    const dim3 blk(256);

    // weights fp32 -> bf16, transposed to [N,K]
    transpose_w_kernel<<<dim3(DIM / 32, DIM / 32), blk, 0, stream>>>(wq, wqT, DIM, DIM);
    transpose_w_kernel<<<dim3(DIM / 32, DIM / 32), blk, 0, stream>>>(wk, wkT, DIM, DIM);
    transpose_w_kernel<<<dim3(DIM / 32, DIM / 32), blk, 0, stream>>>(wv, wvT, DIM, DIM);
    transpose_w_kernel<<<dim3(DIM / 32, DIM / 32), blk, 0, stream>>>(wo, woT, DIM, DIM);
    transpose_w_kernel<<<dim3(HID / 32, DIM / 32), blk, 0, stream>>>(w1, w1T, DIM, HID);
    transpose_w_kernel<<<dim3(DIM / 32, HID / 32), blk, 0, stream>>>(w2, w2T, HID, DIM);

    // xn = rmsnorm(x, attn_norm_w)
    rmsnorm_kernel<<<NROWS, blk, 0, stream>>>(x, anw, xn);

    // q = xn @ wq + bq ; k = xn @ wk + bk
    gemm_kernel<0, 1, 0, 0, 0, 0><<<dim3(DIM / 128, NROWS / 128, 1), blk, 0, stream>>>(
        xn, 0, wqT, 0, q, 0, bq, nullptr, NROWS, DIM, DIM, 1.0f);
    gemm_kernel<0, 1, 0, 0, 0, 0><<<dim3(DIM / 128, NROWS / 128, 1), blk, 0, stream>>>(
        xn, 0, wkT, 0, k, 0, bk, nullptr, NROWS, DIM, DIM, 1.0f);
    // vT[b][d][t] = (wv^T @ xn[b]^T)[d][t] + bv[d]  (bias per row)
    gemm_kernel<0, 2, 0, 0, 0, 0><<<dim3(SEQ / 128, DIM / 128, BATCH), blk, 0, stream>>>(
        wvT, 0, xn, (size_t)SEQ * DIM, vT, (size_t)DIM * SEQ, bv, nullptr, DIM, SEQ, DIM, 1.0f);

    // S[b] = q[b] @ k[b]^T / 32, causal mask, skip upper tiles
    gemm_kernel<0, 0, 0, 0, 1, 0><<<dim3(SEQ / 128, SEQ / 128, BATCH), blk, 0, stream>>>(
        q, (size_t)SEQ * DIM, k, (size_t)SEQ * DIM, S, (size_t)SEQ * SEQ,
        nullptr, nullptr, SEQ, SEQ, DIM, 0.03125f);

    // softmax rows in place
    softmax_kernel<<<dim3(SEQ, BATCH), blk, 0, stream>>>(S);

    // attn[b] = P[b] @ V[b]  (A=S, Bt=vT, causal K-stop)
    gemm_kernel<0, 0, 0, 0, 0, 1><<<dim3(DIM / 128, SEQ / 128, BATCH), blk, 0, stream>>>(
        S, (size_t)SEQ * SEQ, vT, (size_t)DIM * SEQ, attn, (size_t)SEQ * DIM,
        nullptr, nullptr, SEQ, DIM, SEQ, 1.0f);

    // x1 = x + attn @ wo + bo  -> d_out (fp32)
    gemm_kernel<1, 1, 1, 0, 0, 0><<<dim3(DIM / 128, NROWS / 128, 1), blk, 0, stream>>>(
        attn, 0, woT, 0, out, 0, bo, x, NROWS, DIM, DIM, 1.0f);

    // h = rmsnorm(x1, mlp_norm_w)
    rmsnorm_kernel<<<NROWS, blk, 0, stream>>>(out, mnw, h);

    // mid = gelu(h @ w1 + b1)
    gemm_kernel<0, 1, 0, 1, 0, 0><<<dim3(HID / 128, NROWS / 128, 1), blk, 0, stream>>>(
        h, 0, w1T, 0, mid, 0, b1, nullptr, NROWS, HID, DIM, 1.0f);

    // out = x1 + mid @ w2 + b2  (fp32)
    gemm_kernel<1, 1, 1, 0, 0, 0><<<dim3(DIM / 128, NROWS / 128, 1), blk, 0, stream>>>(
        mid, 0, w2T, 0, out, 0, b2, out, NROWS, DIM, HID, 1.0f);
}

// Round 2
// 972.146 us; speedup vs baseline: 1.1513x; 1.1513x over previous
//
#include <hip/hip_runtime.h>
#include <hip/hip_bf16.h>

typedef __bf16 bf16;
typedef __bf16 bf16x8 __attribute__((ext_vector_type(8)));
typedef __bf16 bf16x4 __attribute__((ext_vector_type(4)));
typedef float  f32x4  __attribute__((ext_vector_type(4)));

#define DIM   1024
#define SEQ   2048
#define BATCH 8
#define NROWS (BATCH * SEQ)
#define HID   4096

// ---------------- async global->LDS (16B/lane) ----------------
__device__ __forceinline__ void async_ld16(const bf16* g, bf16* l) {
    __builtin_amdgcn_global_load_lds(
        (__attribute__((address_space(1))) void*)(g),
        (__attribute__((address_space(3))) void*)(l),
        16, 0, 0);
}

__device__ __forceinline__ f32x4 mfma16(bf16x8 a, bf16x8 b, f32x4 c) {
    return __builtin_amdgcn_mfma_f32_16x16x32_bf16(a, b, c, 0, 0, 0);
}

// ---------------- GEMM: C[M,N] = A[M,K] @ Bt[N,K]^T (+epilogue) ----------------
// 128x128 tile, BK=64, 256 threads (4 waves 2x2), 32 MFMA + 16 ds_read_b128
// per barrier pair. LDS chunk XOR-swizzle (phys = data ^ (row&7)) kills the
// quarter-wave 8-way bank conflict of the naive row-major layout.
// BIASMODE: 0 none, 1 bias[n], 2 bias[m]
// SCORE: scale + causal mask (n>m -> -1e30), skip tiles fully above diagonal
// PV: K-loop stops at m0+128 (causal)
template<int OUTF32, int BIASMODE, int RESID, int GELU, int SCORE, int PV>
__global__ __launch_bounds__(256) void gemm_kernel(
    const bf16* __restrict__ A, size_t aB,
    const bf16* __restrict__ B, size_t bB,
    void* __restrict__ Cv, size_t cB,
    const float* __restrict__ bias,
    const float* __restrict__ resid,
    int M, int N, int K, float scale)
{
    __shared__ alignas(16) bf16 As[128 * 64];
    __shared__ alignas(16) bf16 Bs[128 * 64];

    const int m0 = blockIdx.y * 128;
    const int n0 = blockIdx.x * 128;
    if (SCORE && n0 >= m0 + 128) return;   // fully-masked tile: never read downstream

    const int z = blockIdx.z;
    A += (size_t)z * aB;
    B += (size_t)z * bB;

    const int t    = threadIdx.x;
    const int lane = t & 63;
    const int wave = t >> 6;
    const int wm   = wave & 1;
    const int wn   = wave >> 1;

    const int kEnd   = PV ? (m0 + 128) : K;
    const int kIters = kEnd >> 6;

    f32x4 acc[4][4] = {};

    // staging: 8 rows (128B each) per wave per call, 4 calls per matrix.
    // lane l writes LDS phys chunk (l&7) of row (l>>3); XOR-swizzle means it
    // must FETCH global data chunk d = (l&7) ^ ((l>>3)&7).
    const int srow = wave * 8 + (lane >> 3);
    const int scol = (((lane & 7) ^ ((lane >> 3) & 7)) * 8);
    const bf16* gA = A + (size_t)(m0 + srow) * (size_t)K + scol;
    const bf16* gB = B + (size_t)(n0 + srow) * (size_t)K + scol;
    bf16* lA = As + wave * 8 * 64;   // wave-uniform base; HW adds lane*16B
    bf16* lB = Bs + wave * 8 * 64;
    const size_t r32 = (size_t)32 * (size_t)K;

    // fragment read pointers: data chunk c = (lane>>4) + 4*phase, row-swizzled
    const int frow = lane & 15;
    const int cs   = (lane >> 4) ^ (frow & 7);     // phase-0 phys chunk
    const bf16* pa0 = As + (wm * 64 + frow) * 64 + cs * 8;
    const bf16* pa1 = As + (wm * 64 + frow) * 64 + (cs ^ 4) * 8;
    const bf16* pb0 = Bs + (wn * 64 + frow) * 64 + cs * 8;
    const bf16* pb1 = Bs + (wn * 64 + frow) * 64 + (cs ^ 4) * 8;

    for (int kt = 0; kt < kIters; ++kt) {
        #pragma unroll
        for (int j = 0; j < 4; ++j) {
            async_ld16(gA + j * r32, lA + j * 32 * 64);
            async_ld16(gB + j * r32, lB + j * 32 * 64);
        }
        gA += 64; gB += 64;
        __syncthreads();

        {   // phase 0: k 0..31 of this tile
            bf16x8 af[4], bg[4];
            #pragma unroll
            for (int i = 0; i < 4; ++i) af[i] = *(const bf16x8*)(pa0 + i * 16 * 64);
            #pragma unroll
            for (int j = 0; j < 4; ++j) bg[j] = *(const bf16x8*)(pb0 + j * 16 * 64);
            #pragma unroll
            for (int i = 0; i < 4; ++i)
                #pragma unroll
                for (int j = 0; j < 4; ++j)
                    acc[i][j] = mfma16(af[i], bg[j], acc[i][j]);
        }
        {   // phase 1: k 32..63
            bf16x8 af[4], bg[4];
            #pragma unroll
            for (int i = 0; i < 4; ++i) af[i] = *(const bf16x8*)(pa1 + i * 16 * 64);
            #pragma unroll
            for (int j = 0; j < 4; ++j) bg[j] = *(const bf16x8*)(pb1 + j * 16 * 64);
            #pragma unroll
            for (int i = 0; i < 4; ++i)
                #pragma unroll
                for (int j = 0; j < 4; ++j)
                    acc[i][j] = mfma16(af[i], bg[j], acc[i][j]);
        }
        __syncthreads();
    }

    // epilogue: C/D layout col=lane&15, row=(lane>>4)*4+reg  [m89-verified]
    const int col  = lane & 15;
    const int row4 = (lane >> 4) * 4;
    const size_t cOff = (size_t)z * cB;
    #pragma unroll
    for (int i = 0; i < 4; ++i) {
        const int mBase = m0 + wm * 64 + i * 16 + row4;
        #pragma unroll
        for (int j = 0; j < 4; ++j) {
            const int n = n0 + wn * 64 + j * 16 + col;
            const float bcol = (BIASMODE == 1) ? bias[n] : 0.0f;
            #pragma unroll
            for (int r = 0; r < 4; ++r) {
                const int m = mBase + r;
                float v = acc[i][j][r];
                if (BIASMODE == 1) v += bcol;
                if (BIASMODE == 2) v += bias[m];
                if (SCORE) { v *= scale; if (n > m) v = -1e30f; }
                if (GELU)  { v = 0.5f * v * (1.0f + erff(v * 0.70710678118654752f)); }
                const size_t idx = cOff + (size_t)m * (size_t)N + (size_t)n;
                if (RESID) v += resid[idx];
                if (OUTF32) ((float*)Cv)[idx] = v;
                else        ((bf16*)Cv)[idx]  = (bf16)v;
            }
        }
    }
}

// ---------------- RMSNorm: fp32 row(1024) -> bf16 ----------------
__global__ __launch_bounds__(256) void rmsnorm_kernel(
    const float* __restrict__ x, const float* __restrict__ w, bf16* __restrict__ out)
{
    const int row = blockIdx.x;
    const int t   = threadIdx.x;
    const float4 v = ((const float4*)(x + (size_t)row * DIM))[t];
    float ss = v.x * v.x + v.y * v.y + v.z * v.z + v.w * v.w;
    #pragma unroll
    for (int off = 32; off; off >>= 1) ss += __shfl_down(ss, off);
    __shared__ float part[4];
    if ((t & 63) == 0) part[t >> 6] = ss;
    __syncthreads();
    const float tot  = part[0] + part[1] + part[2] + part[3];
    const float rinv = rsqrtf(tot * (1.0f / DIM) + 1e-6f);
    const float4 wv = ((const float4*)w)[t];
    bf16x4 o;
    o[0] = (bf16)(v.x * rinv * wv.x);
    o[1] = (bf16)(v.y * rinv * wv.y);
    o[2] = (bf16)(v.z * rinv * wv.z);
    o[3] = (bf16)(v.w * rinv * wv.w);
    *(bf16x4*)(out + (size_t)row * DIM + t * 4) = o;
}

// ---------------- weight fp32 [R,C] -> bf16 transposed [C,R] ----------------
__global__ __launch_bounds__(256) void transpose_w_kernel(
    const float* __restrict__ src, bf16* __restrict__ dst, int R, int C)
{
    __shared__ float tile[32][33];
    const int tx = threadIdx.x & 31;
    const int ty = threadIdx.x >> 5;     // 0..7
    const int c0 = blockIdx.x * 32;
    const int r0 = blockIdx.y * 32;
    #pragma unroll
    for (int j = 0; j < 32; j += 8)
        tile[ty + j][tx] = src[(size_t)(r0 + ty + j) * C + c0 + tx];
    __syncthreads();
    #pragma unroll
    for (int j = 0; j < 32; j += 8)
        dst[(size_t)(c0 + ty + j) * R + r0 + tx] = (bf16)tile[tx][ty + j];
}

// ---------------- causal softmax over S rows, in place (bf16) ----------------
__global__ __launch_bounds__(256) void softmax_kernel(bf16* __restrict__ S)
{
    const int t = blockIdx.x;
    const int b = blockIdx.y;
    bf16* p = S + ((size_t)b * SEQ + t) * SEQ;
    const int send = ((t >> 7) + 1) << 7;
    const int tid  = threadIdx.x;
    const int lane = tid & 63;
    const int wave = tid >> 6;

    float v[8];
    int cnt = 0;
    float m = -3.0e38f;
    for (int i = tid; i < send; i += 256) { const float f = (float)p[i]; v[cnt++] = f; m = fmaxf(m, f); }
    #pragma unroll
    for (int off = 32; off; off >>= 1) m = fmaxf(m, __shfl_down(m, off));
    __shared__ float red[4];
    if (lane == 0) red[wave] = m;
    __syncthreads();
    m = fmaxf(fmaxf(red[0], red[1]), fmaxf(red[2], red[3]));
    __syncthreads();

    float s = 0.0f;
    for (int k2 = 0; k2 < cnt; ++k2) { v[k2] = __expf(v[k2] - m); s += v[k2]; }
    #pragma unroll
    for (int off = 32; off; off >>= 1) s += __shfl_down(s, off);
    if (lane == 0) red[wave] = s;
    __syncthreads();
    s = red[0] + red[1] + red[2] + red[3];
    const float inv = 1.0f / s;
    cnt = 0;
    for (int i = tid; i < send; i += 256) p[i] = (bf16)(v[cnt++] * inv);
}

extern "C" void kernel_launch(void* const* d_in, const int* in_sizes, int n_in,
                              void* d_out, int out_size, void* d_ws, size_t ws_size,
                              hipStream_t stream)
{
    const float* x   = (const float*)d_in[0];
    const float* anw = (const float*)d_in[1];
    const float* mnw = (const float*)d_in[2];
    const float* wq  = (const float*)d_in[3];
    const float* bq  = (const float*)d_in[4];
    const float* wk  = (const float*)d_in[5];
    const float* bk  = (const float*)d_in[6];
    const float* wv  = (const float*)d_in[7];
    const float* bv  = (const float*)d_in[8];
    const float* wo  = (const float*)d_in[9];
    const float* bo  = (const float*)d_in[10];
    const float* w1  = (const float*)d_in[11];
    const float* b1  = (const float*)d_in[12];
    const float* w2  = (const float*)d_in[13];
    const float* b2  = (const float*)d_in[14];
    float* out = (float*)d_out;

    char* ws = (char*)d_ws;
    const size_t MB = 1024 * 1024;
    bf16* wqT = (bf16*)(ws + 0 * MB);    // 1024x1024  (2 MB)
    bf16* wkT = (bf16*)(ws + 2 * MB);
    bf16* wvT = (bf16*)(ws + 4 * MB);
    bf16* woT = (bf16*)(ws + 6 * MB);
    bf16* w1T = (bf16*)(ws + 8 * MB);    // 4096x1024  (8 MB)
    bf16* w2T = (bf16*)(ws + 16 * MB);   // 1024x4096  (8 MB)
    bf16* xn  = (bf16*)(ws + 24 * MB);   // 16384x1024 (32 MB)
    bf16* q   = (bf16*)(ws + 56 * MB);   // 32 MB
    bf16* k   = (bf16*)(ws + 88 * MB);   // 32 MB
    bf16* vT  = (bf16*)(ws + 120 * MB);  // 8 x 1024 x 2048 (32 MB)
    bf16* S   = (bf16*)(ws + 152 * MB);  // 8 x 2048 x 2048 (64 MB) -> end 216 MB
    bf16* attn = xn;                     // alias: xn dead after vT GEMM
    bf16* h    = q;                      // alias: q dead after score GEMM
    bf16* mid  = k;                      // alias: spans k+vT+S (128 MB), all dead after PV

    const dim3 blk(256);

    // weights fp32 -> bf16, transposed to [N,K]
    transpose_w_kernel<<<dim3(DIM / 32, DIM / 32), blk, 0, stream>>>(wq, wqT, DIM, DIM);
    transpose_w_kernel<<<dim3(DIM / 32, DIM / 32), blk, 0, stream>>>(wk, wkT, DIM, DIM);
    transpose_w_kernel<<<dim3(DIM / 32, DIM / 32), blk, 0, stream>>>(wv, wvT, DIM, DIM);
    transpose_w_kernel<<<dim3(DIM / 32, DIM / 32), blk, 0, stream>>>(wo, woT, DIM, DIM);
    transpose_w_kernel<<<dim3(HID / 32, DIM / 32), blk, 0, stream>>>(w1, w1T, DIM, HID);
    transpose_w_kernel<<<dim3(DIM / 32, HID / 32), blk, 0, stream>>>(w2, w2T, HID, DIM);

    // xn = rmsnorm(x, attn_norm_w)
    rmsnorm_kernel<<<NROWS, blk, 0, stream>>>(x, anw, xn);

    // q = xn @ wq + bq ; k = xn @ wk + bk
    gemm_kernel<0, 1, 0, 0, 0, 0><<<dim3(DIM / 128, NROWS / 128, 1), blk, 0, stream>>>(
        xn, 0, wqT, 0, q, 0, bq, nullptr, NROWS, DIM, DIM, 1.0f);
    gemm_kernel<0, 1, 0, 0, 0, 0><<<dim3(DIM / 128, NROWS / 128, 1), blk, 0, stream>>>(
        xn, 0, wkT, 0, k, 0, bk, nullptr, NROWS, DIM, DIM, 1.0f);
    // vT[b][d][t] = (wv^T @ xn[b]^T)[d][t] + bv[d]  (bias per row)
    gemm_kernel<0, 2, 0, 0, 0, 0><<<dim3(SEQ / 128, DIM / 128, BATCH), blk, 0, stream>>>(
        wvT, 0, xn, (size_t)SEQ * DIM, vT, (size_t)DIM * SEQ, bv, nullptr, DIM, SEQ, DIM, 1.0f);

    // S[b] = q[b] @ k[b]^T / 32, causal mask, skip upper tiles
    gemm_kernel<0, 0, 0, 0, 1, 0><<<dim3(SEQ / 128, SEQ / 128, BATCH), blk, 0, stream>>>(
        q, (size_t)SEQ * DIM, k, (size_t)SEQ * DIM, S, (size_t)SEQ * SEQ,
        nullptr, nullptr, SEQ, SEQ, DIM, 0.03125f);

    // softmax rows in place
    softmax_kernel<<<dim3(SEQ, BATCH), blk, 0, stream>>>(S);

    // attn[b] = P[b] @ V[b]  (A=S, Bt=vT, causal K-stop)
    gemm_kernel<0, 0, 0, 0, 0, 1><<<dim3(DIM / 128, SEQ / 128, BATCH), blk, 0, stream>>>(
        S, (size_t)SEQ * SEQ, vT, (size_t)DIM * SEQ, attn, (size_t)SEQ * DIM,
        nullptr, nullptr, SEQ, DIM, SEQ, 1.0f);

    // x1 = x + attn @ wo + bo  -> d_out (fp32)
    gemm_kernel<1, 1, 1, 0, 0, 0><<<dim3(DIM / 128, NROWS / 128, 1), blk, 0, stream>>>(
        attn, 0, woT, 0, out, 0, bo, x, NROWS, DIM, DIM, 1.0f);

    // h = rmsnorm(x1, mlp_norm_w)
    rmsnorm_kernel<<<NROWS, blk, 0, stream>>>(out, mnw, h);

    // mid = gelu(h @ w1 + b1)
    gemm_kernel<0, 1, 0, 1, 0, 0><<<dim3(HID / 128, NROWS / 128, 1), blk, 0, stream>>>(
        h, 0, w1T, 0, mid, 0, b1, nullptr, NROWS, HID, DIM, 1.0f);

    // out = x1 + mid @ w2 + b2  (fp32)
    gemm_kernel<1, 1, 1, 0, 0, 0><<<dim3(DIM / 128, NROWS / 128, 1), blk, 0, stream>>>(
        mid, 0, w2T, 0, out, 0, b2, out, NROWS, DIM, HID, 1.0f);
}